// Round 2
// baseline (511.004 us; speedup 1.0000x reference)
//
#include <hip/hip_runtime.h>

// CrossEntropyLoss_37254546326109 — fused CE + VAR + Inter + Center loss.
// logit [8,21,512,512] f32, target [8,1,512,512] i32, features [8,262144,32] f32.
// loss = (CE + 1.0*VAR + 0.5*Inter + 0.1*Center)/8, scalar f32 output.
//
// R1 lesson: fp32 atomics = CAS loops; zero fp32 atomics anywhere.
// R2 lesson: main_kernel 175us with VALU 29% / HBM 23% / occ 39% — latency-
//   bound, plus 66 MB scratch-spill traffic (WRITE_SIZE 69 MB vs 2.9 MB
//   explicit). Phase B's 1-deep 16 B/thread register prefetch exposes ~900cy
//   HBM latency per iteration with only 16 waves/CU.
// R3: Phase B now stages feature tiles into LDS via global_load_lds with a
//   double buffer, raw s_barrier + hand-counted vmcnt(2) (never 0 in-loop):
//   8 KB/block permanently in flight, latency structurally hidden.
//   Labels land in LDS during Phase A (it already reads every target), so
//   the Phase B loop touches global memory ONLY via the counted stages.
//   Per-thread pixel order is unchanged -> bitwise-identical accumulation.

constexpr int   N_IMG  = 8;
constexpr int   C_CLS  = 21;
constexpr int   P_PIX  = 512 * 512;     // pixels per image
constexpr int   PQ     = P_PIX / 4;     // float4-quads per image per channel
constexpr int   IGN    = 255;
constexpr float ALPHA  = 1.0f, BETA = 0.5f, GAMMA = 0.1f;

constexpr int MAIN_BLOCKS = 1024;   // 128 per image, 2048 px each (both phases)
constexpr int PX_BLK      = 2048;   // pixels per block
constexpr int TILE_PX     = 64;     // feature pixels per LDS tile (8 KB)
constexpr int NT          = PX_BLK / TILE_PX;   // 32 tiles

// Workspace layout (4-byte units). Total ~2.9 MB.
constexpr int OFF_PIX  = 0;                               // [1024][4] f32
constexpr int OFF_SSQ  = OFF_PIX + MAIN_BLOCKS * 4;       // [1024]    f32
constexpr int OFF_CLS  = OFF_SSQ + MAIN_BLOCKS;           // [1024][672] f32
constexpr int OFF_CNT  = OFF_CLS + MAIN_BLOCKS * 672;     // [1024][21] i32
constexpr int OFF_MEAN = OFF_CNT + MAIN_BLOCKS * C_CLS;   // [168] f32

// async global->LDS, 16 B per lane. LDS dest is wave-uniform base + lane*16.
__device__ __forceinline__ void gl_lds16(const float* g, void* l)
{
    __builtin_amdgcn_global_load_lds(
        (const __attribute__((address_space(1))) void*)g,
        (__attribute__((address_space(3))) void*)l, 16, 0, 0);
}

// ---------------------------------------------------------------------------
// Kernel 1 (fused).
// Phase A (logits): thread = 4 pixels (float4 across pixels, channel stride
// PQ -> coalesced), channels staged in chunks of 7. Also deposits this
// block's 2048 labels into LDS for Phase B.
// Phase B (features): 256 threads = 32 pixel-lanes x 8 dim-groups. Feature
// tiles (64 px x 128 B = 8 KB) double-buffered in LDS via global_load_lds;
// per tile: stage(t+1) -> s_waitcnt vmcnt(2) -> s_barrier -> compute(t)
// [ds_read_b128, bank-even: dg spreads 8x16B clusters] -> s_barrier.
// acc[21] float4 register accumulators, masked FMA (no atomics).
// ---------------------------------------------------------------------------
__global__ __launch_bounds__(256, 4) void main_kernel(
    const float* __restrict__ logit, const int* __restrict__ target,
    const float* __restrict__ feats, float* __restrict__ ws)
{
    // byte map: [0,8K) labels (2048 i32) | [8K,16K) feat buf0 | [16K,24K) buf1
    // after the tile loop, [0,10.75K) is re-purposed as s_part[4][8][21] f4.
    __shared__ __align__(16) char smem[24 * 1024];
    __shared__ int   s_hist[C_CLS];
    __shared__ float s_red[4][4];
    __shared__ float s_ssq[4];

    int* s_lab = (int*)smem;

    const int tid   = threadIdx.x;
    const int img   = blockIdx.x >> 7;       // 128 blocks per image
    const int chunk = blockIdx.x & 127;
    const int p0    = chunk * PX_BLK;

    const float* fbase = feats + ((size_t)img * P_PIX + p0) * 32;

    if (tid < C_CLS) s_hist[tid] = 0;
    __syncthreads();

    // Prologue: stage feature tile 0 into buf0 now; it completes during
    // Phase A. (Phase A's later syncthreads may drain it early — harmless.)
    {
        gl_lds16(fbase + (size_t)tid * 4,
                 smem + 8192 + (size_t)(tid & ~63) * 16);
        gl_lds16(fbase + (size_t)(256 + tid) * 4,
                 smem + 8192 + (size_t)((256 + tid) & ~63) * 16);
    }

    // ---------------- Phase A: logit terms + histogram + label capture ----
    float ce = 0.f, vm = 0.f, var = 0.f, inter = 0.f;

#pragma unroll 1
    for (int qi = 0; qi < 2; ++qi) {
        const int pq = chunk * 512 + qi * 256 + tid;          // quad index
        const int4 t = ((const int4*)target)[(size_t)img * PQ + pq];
        const float4* lp = (const float4*)logit + (size_t)img * C_CLS * PQ + pq;

        // deposit labels for Phase B (local pixel quad qi*256+tid)
        ((int4*)s_lab)[qi * 256 + tid] = t;

        float4 s  = {0.f, 0.f, 0.f, 0.f};
        float4 sc = {0.f, 0.f, 0.f, 0.f};
        float4 lg = {0.f, 0.f, 0.f, 0.f};

#pragma unroll 1
        for (int cb = 0; cb < C_CLS; cb += 7) {
            float4 x[7];
#pragma unroll
            for (int i = 0; i < 7; ++i) x[i] = lp[(size_t)(cb + i) * PQ];
#pragma unroll
            for (int i = 0; i < 7; ++i) {
                const int ch = cb + i;
                const float4 v = x[i];
                s.x += __expf(v.x); s.y += __expf(v.y);
                s.z += __expf(v.z); s.w += __expf(v.w);
                sc.x += v.x; sc.y += v.y; sc.z += v.z; sc.w += v.w;
                lg.x = (t.x == ch) ? v.x : lg.x;
                lg.y = (t.y == ch) ? v.y : lg.y;
                lg.z = (t.z == ch) ? v.z : lg.z;
                lg.w = (t.w == ch) ? v.w : lg.w;
            }
        }

        if (t.x != IGN) atomicAdd(&s_hist[t.x], 1);
        if (t.y != IGN) atomicAdd(&s_hist[t.y], 1);
        if (t.z != IGN) atomicAdd(&s_hist[t.z], 1);
        if (t.w != IGN) atomicAdd(&s_hist[t.w], 1);

        {
            const float v = (t.x != IGN) ? 1.f : 0.f;
            vm += v; ce += v * (__logf(s.x) - lg.x); var -= v * lg.x; inter += v * (sc.x - lg.x);
        }
        {
            const float v = (t.y != IGN) ? 1.f : 0.f;
            vm += v; ce += v * (__logf(s.y) - lg.y); var -= v * lg.y; inter += v * (sc.y - lg.y);
        }
        {
            const float v = (t.z != IGN) ? 1.f : 0.f;
            vm += v; ce += v * (__logf(s.z) - lg.z); var -= v * lg.z; inter += v * (sc.z - lg.z);
        }
        {
            const float v = (t.w != IGN) ? 1.f : 0.f;
            vm += v; ce += v * (__logf(s.w) - lg.w); var -= v * lg.w; inter += v * (sc.w - lg.w);
        }
    }

    for (int off = 32; off; off >>= 1) {
        ce    += __shfl_xor(ce, off);
        vm    += __shfl_xor(vm, off);
        var   += __shfl_xor(var, off);
        inter += __shfl_xor(inter, off);
    }
    const int wv = tid >> 6;
    if ((tid & 63) == 0) {
        s_red[wv][0] = ce; s_red[wv][1] = vm; s_red[wv][2] = var; s_red[wv][3] = inter;
    }
    __syncthreads();   // orders histogram atomics + s_lab writes + s_red

    if (tid < 4) {
        ws[OFF_PIX + blockIdx.x * 4 + tid] =
            s_red[0][tid] + s_red[1][tid] + s_red[2][tid] + s_red[3][tid];
    }
    if (tid < C_CLS) {
        ((int*)ws)[OFF_CNT + blockIdx.x * C_CLS + tid] = s_hist[tid];
    }

    // ---------------- Phase B: center-loss class sums ---------------------
    const int pl = tid >> 3;              // pixel lane 0..31
    const int dg = tid & 7;               // dim group 0..7

    float4 acc[C_CLS];
#pragma unroll
    for (int c = 0; c < C_CLS; ++c) acc[c] = {0.f, 0.f, 0.f, 0.f};
    float ssq = 0.f;

#pragma unroll 1
    for (int tt = 0; tt < NT; ++tt) {
        const float* cur = (const float*)(smem + 8192 + (size_t)(tt & 1) * 8192);
        if (tt + 1 < NT) {
            char* nxt = smem + 8192 + (size_t)((tt + 1) & 1) * 8192;
            const float* g = fbase + (size_t)(tt + 1) * TILE_PX * 32;
            gl_lds16(g + (size_t)tid * 4,         nxt + (size_t)(tid & ~63) * 16);
            gl_lds16(g + (size_t)(256 + tid) * 4, nxt + (size_t)((256 + tid) & ~63) * 16);
            // wait for tile tt's stage (leave the 2 newest in flight)
            asm volatile("s_waitcnt vmcnt(2)" ::: "memory");
        } else {
            asm volatile("s_waitcnt vmcnt(0)" ::: "memory");
        }
        __builtin_amdgcn_s_barrier();      // all waves' stage(tt) complete

#pragma unroll
        for (int h = 0; h < 2; ++h) {
            const int lp2 = h * 32 + pl;
            const int lab = s_lab[tt * TILE_PX + lp2];
            const float4 f = ((const float4*)cur)[lp2 * 8 + dg];
            const float vld = (lab != IGN) ? 1.f : 0.f;
            ssq += vld * (f.x * f.x + f.y * f.y + f.z * f.z + f.w * f.w);
#pragma unroll
            for (int c = 0; c < C_CLS; ++c) {
                const float m = (lab == c) ? 1.f : 0.f;
                acc[c].x += m * f.x; acc[c].y += m * f.y;
                acc[c].z += m * f.z; acc[c].w += m * f.w;
            }
        }
        __builtin_amdgcn_s_barrier();      // buffer reuse guard (tt+2 restage)
    }

    __syncthreads();                       // drain; smem re-purposed below

    // reduce across the 8 pixel-lanes sharing this dim-group within the wave
#pragma unroll
    for (int c = 0; c < C_CLS; ++c) {
        for (int off = 8; off <= 32; off <<= 1) {
            acc[c].x += __shfl_xor(acc[c].x, off);
            acc[c].y += __shfl_xor(acc[c].y, off);
            acc[c].z += __shfl_xor(acc[c].z, off);
            acc[c].w += __shfl_xor(acc[c].w, off);
        }
    }
    for (int off = 1; off < 64; off <<= 1) ssq += __shfl_xor(ssq, off);

    float4* s_part = (float4*)smem;        // [4][8][21], aliases buffers
    if ((tid & 63) < 8) {
#pragma unroll
        for (int c = 0; c < C_CLS; ++c) s_part[(wv * 8 + dg) * C_CLS + c] = acc[c];
    }
    if ((tid & 63) == 0) s_ssq[wv] = ssq;
    __syncthreads();

    if (tid < C_CLS * 8) {                 // 168 threads: one float4 each
        const int c = tid >> 3, g = tid & 7;
        const float4 a = s_part[(0 * 8 + g) * C_CLS + c];
        const float4 b = s_part[(1 * 8 + g) * C_CLS + c];
        const float4 d = s_part[(2 * 8 + g) * C_CLS + c];
        const float4 e = s_part[(3 * 8 + g) * C_CLS + c];
        float4 v;
        v.x = a.x + b.x + d.x + e.x;
        v.y = a.y + b.y + d.y + e.y;
        v.z = a.z + b.z + d.z + e.z;
        v.w = a.w + b.w + d.w + e.w;
        // float offset: blk*672 + c*32 + g*4  (matches reduce_kernel)
        ((float4*)(ws + OFF_CLS))[(size_t)blockIdx.x * 168 + tid] = v;
    }
    if (tid == 0)
        ws[OFF_SSQ + blockIdx.x] = s_ssq[0] + s_ssq[1] + s_ssq[2] + s_ssq[3];
}

// ---------------------------------------------------------------------------
// Kernel 2: fold class-sum partials + count partials into 168 mean-terms.
// One block per (img, class). 128 threads.
// ---------------------------------------------------------------------------
__global__ __launch_bounds__(128) void reduce_kernel(float* __restrict__ ws)
{
    __shared__ float sred[128];
    __shared__ int   s_cnt;

    const int img = blockIdx.x / C_CLS;
    const int c   = blockIdx.x % C_CLS;
    const int tid = threadIdx.x;
    const int d   = tid & 31;         // dim
    const int qq  = tid >> 5;         // 0..3

    if (tid == 0) s_cnt = 0;
    __syncthreads();

    // counts: sum this image's 128 block histograms (one per thread)
    {
        const int* cp = (const int*)ws + OFF_CNT;
        const int cnt = cp[(img * 128 + tid) * C_CLS + c];
        atomicAdd(&s_cnt, cnt);
    }

    // class sums: sum this image's 128 block partials for (c, d)
    float s = 0.f;
    for (int b = qq; b < 128; b += 4)
        s += ws[OFF_CLS + (size_t)(img * 128 + b) * 672 + c * 32 + d];
    sred[tid] = s;
    __syncthreads();                  // also orders s_cnt atomics
    if (tid < 64) sred[tid] += sred[tid + 64];
    __syncthreads();
    if (tid < 32) {
        const float Sd = sred[tid] + sred[tid + 32];
        float n2 = Sd * Sd;
        for (int off = 1; off < 32; off <<= 1) n2 += __shfl_xor(n2, off);
        if (tid == 0)
            ws[OFF_MEAN + blockIdx.x] = n2 / fmaxf((float)s_cnt, 1.f);
    }
}

// ---------------------------------------------------------------------------
// Kernel 3: final combine.
// ---------------------------------------------------------------------------
__global__ __launch_bounds__(256) void finalize_kernel(
    const float* __restrict__ ws, float* __restrict__ out)
{
    __shared__ float fr[4][6];
    const int tid = threadIdx.x;

    float ce = 0.f, vm = 0.f, var = 0.f, inter = 0.f, ssq = 0.f, mean = 0.f;
    for (int b = tid; b < MAIN_BLOCKS; b += 256) {
        const float* p = ws + OFF_PIX + b * 4;
        ce += p[0]; vm += p[1]; var += p[2]; inter += p[3];
        ssq += ws[OFF_SSQ + b];
    }
    if (tid < N_IMG * C_CLS) mean = ws[OFF_MEAN + tid];

    for (int off = 32; off; off >>= 1) {
        ce   += __shfl_xor(ce, off);   vm    += __shfl_xor(vm, off);
        var  += __shfl_xor(var, off);  inter += __shfl_xor(inter, off);
        ssq  += __shfl_xor(ssq, off);  mean  += __shfl_xor(mean, off);
    }
    const int wv = tid >> 6;
    if ((tid & 63) == 0) {
        fr[wv][0] = ce;  fr[wv][1] = vm;   fr[wv][2] = var;
        fr[wv][3] = inter; fr[wv][4] = ssq; fr[wv][5] = mean;
    }
    __syncthreads();
    if (tid == 0) {
        const float CE_s  = fr[0][0] + fr[1][0] + fr[2][0] + fr[3][0];
        const float VM    = fr[0][1] + fr[1][1] + fr[2][1] + fr[3][1];
        const float VAR_s = fr[0][2] + fr[1][2] + fr[2][2] + fr[3][2];
        const float INT_s = fr[0][3] + fr[1][3] + fr[2][3] + fr[3][3];
        const float SSQ   = fr[0][4] + fr[1][4] + fr[2][4] + fr[3][4];
        const float MEAN  = fr[0][5] + fr[1][5] + fr[2][5] + fr[3][5];
        const float invP   = 1.f / (float)P_PIX;
        const float CE     = CE_s / fmaxf(VM, 1.f);
        const float VAR    = VAR_s * invP;
        const float Inter  = INT_s * invP;
        const float Center = (SSQ - MEAN) * invP;
        out[0] = (CE + ALPHA * VAR + BETA * Inter + GAMMA * Center) / (float)N_IMG;
    }
}

extern "C" void kernel_launch(void* const* d_in, const int* in_sizes, int n_in,
                              void* d_out, int out_size, void* d_ws, size_t ws_size,
                              hipStream_t stream)
{
    const float* logit  = (const float*)d_in[0];
    const int*   target = (const int*)d_in[1];
    const float* feats  = (const float*)d_in[2];
    float* ws  = (float*)d_ws;
    float* out = (float*)d_out;

    // No memset needed: every ws word consumed is written earlier in-stream.
    main_kernel    <<<MAIN_BLOCKS, 256, 0, stream>>>(logit, target, feats, ws);
    reduce_kernel  <<<N_IMG * C_CLS, 128, 0, stream>>>(ws);
    finalize_kernel<<<1, 256, 0, stream>>>(ws, out);
}